// Round 6
// baseline (672.859 us; speedup 1.0000x reference)
//
#include <hip/hip_runtime.h>

#define T 2048
#define D 1024
#define F 4096
#define E 8
#define NS 8
#define FS 512
#define SHB 5120      // shared-expert H base row (routed padded capacity)
#define NROWS 7168    // SHB + T
#define MT_MAX 56     // NROWS/128

typedef float floatx4 __attribute__((ext_vector_type(4)));
typedef short short8 __attribute__((ext_vector_type(8)));
typedef unsigned short ushort8v __attribute__((ext_vector_type(8)));

__device__ __forceinline__ unsigned short f2bf(float f) {
  unsigned int u = __float_as_uint(f);
  u += 0x7FFF + ((u >> 16) & 1);   // RNE
  return (unsigned short)(u >> 16);
}

__device__ __forceinline__ void glds16(const void* g, void* l) {
  __builtin_amdgcn_global_load_lds(
      (const __attribute__((address_space(1))) void*)g,
      (__attribute__((address_space(3))) void*)l, 16, 0, 0);
}

// route: find expert segment for a 128-row tile at row r0b; returns e (E = shared,
// -1 = dead padding zone), segment base row (obase) and real count (ccnt).
__device__ __forceinline__ int route(const int* __restrict__ cnt, int r0b,
                                     int& obase, int& ccnt) {
  int e = -1, o = 0, ob = 0, cc = 0;
#pragma unroll
  for (int i = 0; i < E; ++i) {
    int c = cnt[i];
    int p = (c + 127) & ~127;
    if (r0b >= o && r0b < o + p) { e = i; ob = o; cc = c; }
    o += p;
  }
  if (r0b >= SHB) e = E;
  obase = ob; ccnt = cc;
  return e;
}

// off[e] without a dynamically-indexed array (branch-free).
__device__ __forceinline__ int seg_off(const int* __restrict__ cnt, int e) {
  int o = 0;
#pragma unroll
  for (int i = 0; i < E; ++i) { int p = (cnt[i] + 127) & ~127; o += (i < e) ? p : 0; }
  return o;
}

// ------- transpose+cast fp32 [R,C] -> bf16 B^T tiled [C/128][R/32][128][32] -------
// 32r x 256c tile, 256 threads. Reads: each wave-instruction covers ONE FULL ROW
// (1 KB contiguous) -> good DRAM page locality (the 64x64 tile's 256 B segments
// at 16 KB stride were the prior BW killer). LDS [32][260]: row stride 1040 B
// (16B-aligned ds_write_b128); read phase lane-per-column -> (4r+c)&31, 2-way max.
// Writes: thread owns one output column; its 4 ushort8 tile a contiguous 64 B;
// a wave writes 4 KB fully contiguous.
__device__ __forceinline__ void tc32(const float* __restrict__ in,
                                     unsigned short* __restrict__ out, int R, int C,
                                     int bx, int by, float (*tile)[260]) {
  int tid = threadIdx.x;
  int r0 = by * 32, c0 = bx * 256;
  int rl = tid >> 6;                 // 0..3
  int cl = (tid & 63) * 4;           // float col within the 256-col tile
  const float* src = in + (size_t)(r0 + rl) * C + c0 + cl;
#pragma unroll
  for (int i = 0; i < 8; ++i) {
    float4 v = *(const float4*)(src + (size_t)(4 * i) * C);
    *(float4*)&tile[rl + 4 * i][cl] = v;     // 16B-aligned ds_write_b128
  }
  __syncthreads();
  int c = c0 + tid;
  int Rt = R >> 5;
  size_t o0 = ((size_t)(c >> 7) * Rt + by) * 4096 + (size_t)(c & 127) * 32;
#pragma unroll
  for (int j = 0; j < 4; ++j) {
    ushort8v v;
#pragma unroll
    for (int k = 0; k < 8; ++k) v[k] = f2bf(tile[j * 8 + k][tid]);
    *(ushort8v*)(out + o0 + j * 8) = v;      // 16B store, contiguous per lane
  }
}

// ---------------- gate body: logits, softmax, top-2, x -> bf16 ----------------
__device__ __forceinline__ void gate_body(const float* __restrict__ x,
                                          const float* __restrict__ gW,
                                          unsigned short* __restrict__ xb,
                                          int* __restrict__ cnt,
                                          int* __restrict__ list_tok,
                                          float* __restrict__ list_gate,
                                          int* __restrict__ assign, int t, float* wred) {
  int tid = threadIdx.x;
  const float4* xr = (const float4*)(x + (size_t)t * D);
  const float4* g4 = (const float4*)gW;
  float4 xv = xr[tid];                       // D/4 = 256 = blockDim
  ushort4 xo;
  xo.x = f2bf(xv.x); xo.y = f2bf(xv.y); xo.z = f2bf(xv.z); xo.w = f2bf(xv.w);
  *(ushort4*)(xb + (size_t)t * D + tid * 4) = xo;
  float acc[E];
#pragma unroll
  for (int e = 0; e < E; ++e) {
    float4 w = g4[e * 256 + tid];
    acc[e] = xv.x * w.x + xv.y * w.y + xv.z * w.z + xv.w * w.w;
  }
#pragma unroll
  for (int o = 32; o > 0; o >>= 1)
#pragma unroll
    for (int e = 0; e < E; ++e) acc[e] += __shfl_down(acc[e], o, 64);
  int lane = tid & 63, wv = tid >> 6;
  if (lane == 0)
#pragma unroll
    for (int e = 0; e < E; ++e) wred[wv * E + e] = acc[e];
  __syncthreads();
  if (tid == 0) {
    float l[E];
#pragma unroll
    for (int e = 0; e < E; ++e) l[e] = wred[0 * E + e] + wred[1 * E + e] + wred[2 * E + e] + wred[3 * E + e];
    int i1 = 0; float m1 = l[0];
    for (int e = 1; e < E; ++e) if (l[e] > m1) { m1 = l[e]; i1 = e; }
    int i2 = -1; float m2 = -3.4e38f;
    for (int e = 0; e < E; ++e) if (e != i1 && l[e] > m2) { m2 = l[e]; i2 = e; }
    float s = 0.f, p[E];
#pragma unroll
    for (int e = 0; e < E; ++e) { p[e] = __expf(l[e] - m1); s += p[e]; }
    float inv = 1.f / s;
    int p1 = atomicAdd(&cnt[i1], 1);
    list_tok[i1 * T + p1] = t; list_gate[i1 * T + p1] = p[i1] * inv;
    assign[2 * t] = (i1 << 16) | p1;
    int p2 = atomicAdd(&cnt[i2], 1);
    list_tok[i2 * T + p2] = t; list_gate[i2 * T + p2] = p[i2] * inv;
    assign[2 * t + 1] = (i2 << 16) | p2;
  }
}

// ---------------- prep: ALL weight transposes + gate in ONE launch ----------------
// Flat block-id segments (32x256 tiles):
//   [0,4096)       w1e: z=t>>9, rem=t&511, bx=rem&15, by=rem>>4   (R=D,C=F)
//   [4096,8192)    w3e: same
//   [8192,12288)   w2e: z=t>>9, rem=t&511, bx=rem&3,  by=rem>>2   (R=F,C=D)
//   [12288,12800)  w1s: z=t>>6, rem=t&63,  bx=rem&1,  by=rem>>1   (R=D,C=FS)
//   [12800,13312)  w3s: same
//   [13312,13824)  w2s: bx=t&3, by=t>>2                           (R=F,C=D, single)
//   [13824,15872)  gate for token t
__global__ void prep_kernel(const float* __restrict__ x, const float* __restrict__ gW,
                            const float* __restrict__ w1e, const float* __restrict__ w3e,
                            const float* __restrict__ w2e, const float* __restrict__ w1s,
                            const float* __restrict__ w3s, const float* __restrict__ w2s,
                            unsigned short* __restrict__ W1T, unsigned short* __restrict__ W3T,
                            unsigned short* __restrict__ W2T, unsigned short* __restrict__ W1sT,
                            unsigned short* __restrict__ W3sT, unsigned short* __restrict__ W2sT,
                            unsigned short* __restrict__ xb, int* __restrict__ cnt,
                            int* __restrict__ list_tok, float* __restrict__ list_gate,
                            int* __restrict__ assign) {
  __shared__ float tile[32][260];
  int bid = blockIdx.x;
  if (bid < 4096) {
    int z = bid >> 9, rem = bid & 511;
    tc32(w1e + (size_t)z * D * F, W1T + (size_t)z * D * F, D, F, rem & 15, rem >> 4, tile);
  } else if (bid < 8192) {
    int t = bid - 4096;
    int z = t >> 9, rem = t & 511;
    tc32(w3e + (size_t)z * D * F, W3T + (size_t)z * D * F, D, F, rem & 15, rem >> 4, tile);
  } else if (bid < 12288) {
    int t = bid - 8192;
    int z = t >> 9, rem = t & 511;
    tc32(w2e + (size_t)z * F * D, W2T + (size_t)z * F * D, F, D, rem & 3, rem >> 2, tile);
  } else if (bid < 12800) {
    int t = bid - 12288;
    int z = t >> 6, rem = t & 63;
    tc32(w1s + (size_t)z * D * FS, W1sT + (size_t)z * D * FS, D, FS, rem & 1, rem >> 1, tile);
  } else if (bid < 13312) {
    int t = bid - 12800;
    int z = t >> 6, rem = t & 63;
    tc32(w3s + (size_t)z * D * FS, W3sT + (size_t)z * D * FS, D, FS, rem & 1, rem >> 1, tile);
  } else if (bid < 13824) {
    int t = bid - 13312;
    tc32(w2s, W2sT, F, D, t & 3, t >> 2, tile);
  } else {
    gate_body(x, gW, xb, cnt, list_tok, list_gate, assign, bid - 13824, (float*)tile);
  }
}

// ---------------- up GEMM: H = silu(A@W1) * (A@W3), grouped by expert ----------------
// Depth-2 pipeline (T4 counted-vmcnt): 3 static LDS buffers, raw s_barrier, manual
// s_waitcnt vmcnt(6) (= one stage's glds count) so a full stage stays in flight
// across each barrier. Iteration: [stage(t+2); compute(t); vmcnt(6); s_barrier].
// LDS XOR-swizzle: 16B slot j of row r holds global slot j ^ ((r>>1)&3).
__global__ __launch_bounds__(256, 2) void up_gemm(
    const unsigned short* __restrict__ xb, const unsigned short* __restrict__ W1T,
    const unsigned short* __restrict__ W3T, const unsigned short* __restrict__ W1sT,
    const unsigned short* __restrict__ W3sT, const int* __restrict__ cnt,
    const int* __restrict__ list_tok, unsigned short* __restrict__ Hb) {
  int mt = blockIdx.y, ntile = blockIdx.x;
  int obase, ccnt;
  int e = route(cnt, mt * 128, obase, ccnt);
  if (e < 0) return;
  const unsigned short *B1, *B3;
  if (e < E) {
    B1 = W1T + (size_t)e * F * D;
    B3 = W3T + (size_t)e * F * D;
  } else {
    B1 = W1sT; B3 = W3sT;
  }
  __shared__ unsigned short Au0[128 * 32], B1u0[128 * 32], B3u0[128 * 32];
  __shared__ unsigned short Au1[128 * 32], B1u1[128 * 32], B3u1[128 * 32];
  __shared__ unsigned short Au2[128 * 32], B1u2[128 * 32], B3u2[128 * 32];
  int tid = threadIdx.x;
  int lane = tid & 63, wv = tid >> 6, wm = wv >> 1, wn = wv & 1;
  int row16 = lane & 15, quad = lane >> 4;
  int qsw8 = (quad ^ ((lane >> 1) & 3)) * 8;   // swizzled read slot, in shorts
  int swzb = (tid >> 2) * 64 + (((tid & 3) ^ ((tid >> 3) & 3)) * 16);  // staging src byte off
  int lw = wv * 1024;  // wave LDS byte offset (glds dest must be wave-uniform)

  int r1 = tid >> 2;
  int hrow1 = mt * 128 + r1, hrow2 = hrow1 + 64;
  int srow1, srow2;
  if (e < E) {
    int i1 = hrow1 - obase; i1 = (i1 < ccnt) ? i1 : ccnt - 1;
    int i2 = hrow2 - obase; i2 = (i2 < ccnt) ? i2 : ccnt - 1;
    srow1 = list_tok[e * T + i1];
    srow2 = list_tok[e * T + i2];
  } else {
    srow1 = hrow1 - SHB; srow2 = hrow2 - SHB;
  }
  int asl = ((tid & 3) ^ ((tid >> 3) & 3)) * 16;
  const char* asrc1 = (const char*)(xb + (size_t)srow1 * D) + asl;
  const char* asrc2 = (const char*)(xb + (size_t)srow2 * D) + asl;
  const char* b1t = (const char*)(B1 + (size_t)ntile * (D / 32) * 4096);
  const char* b3t = (const char*)(B3 + (size_t)ntile * (D / 32) * 4096);

  floatx4 accg[4][4], accu[4][4];
#pragma unroll
  for (int i = 0; i < 4; ++i)
#pragma unroll
    for (int j = 0; j < 4; ++j) {
      accg[i][j] = (floatx4){0.f, 0.f, 0.f, 0.f};
      accu[i][j] = (floatx4){0.f, 0.f, 0.f, 0.f};
    }

  auto stage = [&](int kt, unsigned short* Ad, unsigned short* B1d, unsigned short* B3d) {
    size_t ko = (size_t)kt * 64;     // A advances 32 bf16 = 64 B per K-step
    size_t bo = (size_t)kt * 8192;   // B tile = 8 KB per K-step
    glds16(asrc1 + ko, (char*)Ad + lw);
    glds16(asrc2 + ko, (char*)Ad + 4096 + lw);
    glds16(b1t + bo + swzb, (char*)B1d + lw);
    glds16(b1t + bo + 4096 + swzb, (char*)B1d + 4096 + lw);
    glds16(b3t + bo + swzb, (char*)B3d + lw);
    glds16(b3t + bo + 4096 + swzb, (char*)B3d + 4096 + lw);
  };
  auto compute = [&](const unsigned short* Ac, const unsigned short* B1c,
                     const unsigned short* B3c) {
    short8 af[4], b1f[4], b3f[4];
#pragma unroll
    for (int mi = 0; mi < 4; ++mi)
      af[mi] = *(const short8*)(Ac + (wm * 64 + mi * 16 + row16) * 32 + qsw8);
#pragma unroll
    for (int ni = 0; ni < 4; ++ni) {
      b1f[ni] = *(const short8*)(B1c + (wn * 64 + ni * 16 + row16) * 32 + qsw8);
      b3f[ni] = *(const short8*)(B3c + (wn * 64 + ni * 16 + row16) * 32 + qsw8);
    }
#pragma unroll
    for (int mi = 0; mi < 4; ++mi)
#pragma unroll
      for (int ni = 0; ni < 4; ++ni) {
        accg[mi][ni] = __builtin_amdgcn_mfma_f32_16x16x32_bf16(af[mi], b1f[ni], accg[mi][ni], 0, 0, 0);
        accu[mi][ni] = __builtin_amdgcn_mfma_f32_16x16x32_bf16(af[mi], b3f[ni], accu[mi][ni], 0, 0, 0);
      }
  };

  stage(0, Au0, B1u0, B3u0);
  stage(1, Au1, B1u1, B3u1);
  asm volatile("s_waitcnt vmcnt(6)" ::: "memory");   // stage(0) landed
  __builtin_amdgcn_s_barrier();
  for (int t = 0; t < 30; t += 3) {
    stage(t + 2, Au2, B1u2, B3u2);
    compute(Au0, B1u0, B3u0);
    asm volatile("s_waitcnt vmcnt(6)" ::: "memory");
    __builtin_amdgcn_s_barrier();
    stage(t + 3, Au0, B1u0, B3u0);
    compute(Au1, B1u1, B3u1);
    asm volatile("s_waitcnt vmcnt(6)" ::: "memory");
    __builtin_amdgcn_s_barrier();
    stage(t + 4, Au1, B1u1, B3u1);
    compute(Au2, B1u2, B3u2);
    asm volatile("s_waitcnt vmcnt(6)" ::: "memory");
    __builtin_amdgcn_s_barrier();
  }
  compute(Au0, B1u0, B3u0);            // t=30
  asm volatile("s_waitcnt vmcnt(0)" ::: "memory");   // stage(31) landed
  __builtin_amdgcn_s_barrier();
  compute(Au1, B1u1, B3u1);            // t=31

  // epilogue: silu(g)*u -> bf16, H in tiled layout
#pragma unroll
  for (int mi = 0; mi < 4; ++mi)
#pragma unroll
    for (int ni = 0; ni < 4; ++ni)
#pragma unroll
      for (int r = 0; r < 4; ++r) {
        int hrow = mt * 128 + wm * 64 + mi * 16 + quad * 4 + r;
        int col = ntile * 128 + wn * 64 + ni * 16 + row16;
        float g = accg[mi][ni][r], u = accu[mi][ni][r];
        float h = g * u / (1.0f + __expf(-g));
        size_t o = ((size_t)(hrow >> 7) * 128 + (col >> 5)) * 4096 + (size_t)(hrow & 127) * 32 + (col & 31);
        Hb[o] = f2bf(h);
      }
}

// ---------------- down GEMM: O = (H @ W2) * gate_scale, full-K ----------------
// Same depth-2 counted-vmcnt pipeline; stage width = 4 glds -> vmcnt(4). 128 K-steps.
__global__ __launch_bounds__(256, 2) void down_gemm(
    const unsigned short* __restrict__ Hb, const unsigned short* __restrict__ W2T,
    const unsigned short* __restrict__ W2sT, const int* __restrict__ cnt,
    const float* __restrict__ list_gate, float* __restrict__ O) {
  int mt = blockIdx.y, ntile = blockIdx.x;
  int obase, ccnt;
  int e = route(cnt, mt * 128, obase, ccnt);
  if (e < 0) return;
  const char* Bt = (const char*)(((e < E) ? (W2T + (size_t)e * D * F) : W2sT)
                                 + (size_t)ntile * (F / 32) * 4096);
  const char* At = (const char*)(Hb + (size_t)mt * (F / 32) * 4096);
  __shared__ unsigned short Ad0[128 * 32], Bd0[128 * 32];
  __shared__ unsigned short Ad1[128 * 32], Bd1[128 * 32];
  __shared__ unsigned short Ad2[128 * 32], Bd2[128 * 32];
  int tid = threadIdx.x;
  int lane = tid & 63, wv = tid >> 6, wm = wv >> 1, wn = wv & 1;
  int row16 = lane & 15, quad = lane >> 4;
  int qsw8 = (quad ^ ((lane >> 1) & 3)) * 8;
  int swzb = (tid >> 2) * 64 + (((tid & 3) ^ ((tid >> 3) & 3)) * 16);
  int lw = wv * 1024;
  floatx4 acc[4][4];
#pragma unroll
  for (int i = 0; i < 4; ++i)
#pragma unroll
    for (int j = 0; j < 4; ++j) acc[i][j] = (floatx4){0.f, 0.f, 0.f, 0.f};

  auto stage = [&](int kt, unsigned short* Ad, unsigned short* Bd) {
    size_t o = (size_t)kt * 8192;
    glds16(At + o + swzb, (char*)Ad + lw);
    glds16(At + o + 4096 + swzb, (char*)Ad + 4096 + lw);
    glds16(Bt + o + swzb, (char*)Bd + lw);
    glds16(Bt + o + 4096 + swzb, (char*)Bd + 4096 + lw);
  };
  auto compute = [&](const unsigned short* Ac, const unsigned short* Bc) {
    short8 af[4], bf[4];
#pragma unroll
    for (int mi = 0; mi < 4; ++mi)
      af[mi] = *(const short8*)(Ac + (wm * 64 + mi * 16 + row16) * 32 + qsw8);
#pragma unroll
    for (int ni = 0; ni < 4; ++ni)
      bf[ni] = *(const short8*)(Bc + (wn * 64 + ni * 16 + row16) * 32 + qsw8);
#pragma unroll
    for (int mi = 0; mi < 4; ++mi)
#pragma unroll
      for (int ni = 0; ni < 4; ++ni)
        acc[mi][ni] = __builtin_amdgcn_mfma_f32_16x16x32_bf16(af[mi], bf[ni], acc[mi][ni], 0, 0, 0);
  };

  stage(0, Ad0, Bd0);
  stage(1, Ad1, Bd1);
  asm volatile("s_waitcnt vmcnt(4)" ::: "memory");   // stage(0) landed
  __builtin_amdgcn_s_barrier();
  for (int t = 0; t < 126; t += 3) {
    stage(t + 2, Ad2, Bd2);
    compute(Ad0, Bd0);
    asm volatile("s_waitcnt vmcnt(4)" ::: "memory");
    __builtin_amdgcn_s_barrier();
    stage(t + 3, Ad0, Bd0);
    compute(Ad1, Bd1);
    asm volatile("s_waitcnt vmcnt(4)" ::: "memory");
    __builtin_amdgcn_s_barrier();
    stage(t + 4, Ad1, Bd1);
    compute(Ad2, Bd2);
    asm volatile("s_waitcnt vmcnt(4)" ::: "memory");
    __builtin_amdgcn_s_barrier();
  }
  compute(Ad0, Bd0);                   // t=126
  asm volatile("s_waitcnt vmcnt(0)" ::: "memory");   // stage(127) landed
  __builtin_amdgcn_s_barrier();
  compute(Ad1, Bd1);                   // t=127

#pragma unroll
  for (int mi = 0; mi < 4; ++mi)
#pragma unroll
    for (int ni = 0; ni < 4; ++ni)
#pragma unroll
      for (int r = 0; r < 4; ++r) {
        int grow = mt * 128 + wm * 64 + mi * 16 + quad * 4 + r;
        int col = ntile * 128 + wn * 64 + ni * 16 + row16;
        float scale;
        if (e < E) {
          int i = grow - obase;
          scale = (i < ccnt) ? 0.5f * list_gate[e * T + i] : 0.0f;
        } else {
          scale = 0.0625f;
        }
        O[(size_t)grow * D + col] = acc[mi][ni][r] * scale;
      }
}

// ---------------- combine: out = r0 + r1 + shared (rows from assign+cnt) ----------------
__global__ void combine_kernel(const float* __restrict__ O, const int* __restrict__ cnt,
                               const int* __restrict__ assign, float* __restrict__ out) {
  int idx = blockIdx.x * 256 + threadIdx.x;  // T * D/4
  int t = idx >> 8, c = idx & 255;
  int a0 = assign[2 * t], a1 = assign[2 * t + 1];
  int r0 = seg_off(cnt, a0 >> 16) + (a0 & 0xFFFF);
  int r1 = seg_off(cnt, a1 >> 16) + (a1 & 0xFFFF);
  const float4* O4 = (const float4*)O;
  float4 a = O4[(size_t)r0 * 256 + c];
  float4 b = O4[(size_t)r1 * 256 + c];
  float4 s = O4[((size_t)SHB + t) * 256 + c];
  float4 r;
  r.x = a.x + b.x + s.x;
  r.y = a.y + b.y + s.y;
  r.z = a.z + b.z + s.z;
  r.w = a.w + b.w + s.w;
  ((float4*)out)[idx] = r;
}

extern "C" void kernel_launch(void* const* d_in, const int* in_sizes, int n_in,
                              void* d_out, int out_size, void* d_ws, size_t ws_size,
                              hipStream_t stream) {
  (void)in_sizes; (void)n_in; (void)out_size; (void)ws_size;
  const float* x   = (const float*)d_in[0];
  const float* gW  = (const float*)d_in[1];
  const float* w1e = (const float*)d_in[2];
  const float* w3e = (const float*)d_in[3];
  const float* w2e = (const float*)d_in[4];
  const float* w1s = (const float*)d_in[5];
  const float* w3s = (const float*)d_in[6];
  const float* w2s = (const float*)d_in[7];
  float* out = (float*)d_out;

  char* w = (char*)d_ws;
  auto alloc = [&](size_t bytes) {
    char* p = w; w += (bytes + 255) & ~(size_t)255; return p;
  };
  unsigned short* xb   = (unsigned short*)alloc((size_t)T * D * 2);
  unsigned short* W1T  = (unsigned short*)alloc((size_t)E * F * D * 2);
  unsigned short* W3T  = (unsigned short*)alloc((size_t)E * F * D * 2);
  unsigned short* W2T  = (unsigned short*)alloc((size_t)E * D * F * 2);
  unsigned short* W1sT = (unsigned short*)alloc((size_t)F * D * 2);
  unsigned short* W3sT = (unsigned short*)alloc((size_t)F * D * 2);
  unsigned short* W2sT = (unsigned short*)alloc((size_t)D * F * 2);
  unsigned short* Hb   = (unsigned short*)alloc((size_t)NROWS * F * 2);
  float* Ob        = (float*)alloc((size_t)NROWS * D * 4);
  float* list_gate = (float*)alloc((size_t)E * T * 4);
  int* list_tok    = (int*)alloc((size_t)E * T * 4);
  int* assign      = (int*)alloc((size_t)T * 2 * 4);
  int* cnt         = (int*)alloc(E * 4);

  hipMemsetAsync(cnt, 0, E * 4, stream);
  prep_kernel<<<15872, 256, 0, stream>>>(x, gW, w1e, w3e, w2e, w1s, w3s, w2s,
                                         W1T, W3T, W2T, W1sT, W3sT, W2sT,
                                         xb, cnt, list_tok, list_gate, assign);
  up_gemm<<<dim3(F / 128, MT_MAX), 256, 0, stream>>>(xb, W1T, W3T, W1sT, W3sT,
                                                     cnt, list_tok, Hb);
  down_gemm<<<dim3(D / 128, MT_MAX), 256, 0, stream>>>(Hb, W2T, W2sT, cnt, list_gate, Ob);
  combine_kernel<<<(T * D / 4) / 256, 256, 0, stream>>>(Ob, cnt, assign, out);
}